// Round 1
// baseline (5178.580 us; speedup 1.0000x reference)
//
#include <hip/hip_runtime.h>

#define T_STEPS 784
#define H 512
#define NBATCH 128
#define OUTC 10

// out layout (floats): outputs[128*10] | fr1[128*512] | fr2 | fr3 | layer_fr[3]
#define OFF_OUT   0
#define OFF_FR1   1280
#define OFF_FR2   66816
#define OFF_FR3   132352
#define OFF_LFR   197888

__global__ __launch_bounds__(256) void prep_kernel(
    const float* __restrict__ W2, const float* __restrict__ W3,
    const float* __restrict__ m1, const float* __restrict__ m2, const float* __restrict__ m3,
    float* __restrict__ W2T, float* __restrict__ W3T,
    unsigned char* __restrict__ m1T, unsigned char* __restrict__ m2T,
    unsigned char* __restrict__ m3T, float* __restrict__ out_tail)
{
    int tid = blockIdx.x * blockDim.x + threadIdx.x;
    int stride = gridDim.x * blockDim.x;
    // transpose W2, W3: W2T[i*H+j] = W2[j*H+i]
    for (int p = tid; p < H * H; p += stride) {
        int i = p >> 9, j = p & (H - 1);
        W2T[p] = W2[j * H + i];
        W3T[p] = W3[j * H + i];
    }
    // masks: [dim][T] fp32 -> [t][dim] u8
    for (int p = tid; p < T_STEPS * H; p += stride) {
        int t = p >> 9, i = p & (H - 1);
        m1T[p] = (m1[i * T_STEPS + t] != 0.f) ? 1 : 0;
        m2T[p] = (m2[i * T_STEPS + t] != 0.f) ? 1 : 0;
        m3T[p] = (m3[i * T_STEPS + t] != 0.f) ? 1 : 0;
    }
    if (tid < 3) out_tail[tid] = 0.f;  // layer_fr accumulators
}

__global__ __launch_bounds__(512) void snn_kernel(
    const float* __restrict__ x,
    const float* __restrict__ W1, const float* __restrict__ b1,
    const float* __restrict__ b2, const float* __restrict__ b3,
    const float* __restrict__ W4, const float* __restrict__ b4,
    const float* __restrict__ W2T, const float* __restrict__ W3T,
    const unsigned char* __restrict__ m1T, const unsigned char* __restrict__ m2T,
    const unsigned char* __restrict__ m3T,
    float* __restrict__ out)
{
    const int n = blockIdx.x;      // sample
    const int j = threadIdx.x;     // neuron (same index in all 3 layers)
    const int lane = j & 63;
    const int wid = j >> 6;        // 8 waves

    __shared__ float x_lds[T_STEPS];
    __shared__ short list1[H];     // per-wave segments: [wid*64 .. wid*64+wcnt)
    __shared__ short list2[H];
    __shared__ int wcnt1[8], wcnt2[8];
    __shared__ float acc10[16];
    __shared__ float rsum[3];

    for (int t = j; t < T_STEPS; t += 512) x_lds[t] = x[n * T_STEPS + t];

    float mem1 = 0.f, mem2 = 0.f, mem3 = 0.f;
    float s1 = 0.f, s2 = 0.f, s3 = 0.f;      // previous-step spikes (carry)
    float c1 = 0.f, c2 = 0.f, c3 = 0.f;      // spike-count accumulators
    const float w1  = W1[j];
    const float b1v = b1[j], b2v = b2[j], b3v = b3[j];
    const unsigned long long lt_mask = (1ull << lane) - 1ull;

    __syncthreads();

    for (int t = 0; t < T_STEPS; ++t) {
        const bool k1 = m1T[t * H + j] != 0;
        const bool k2 = m2T[t * H + j] != 0;
        const bool k3 = m3T[t * H + j] != 0;

        // ---- Layer 1 (elementwise: inp @ W1.T = x_t * W1[j]) ----
        {
            float nm = mem1 * (0.2f * (1.f - s1)) + x_lds[t] * w1 + b1v;
            if (k1) mem1 = nm;
            bool f = k1 && (mem1 > 0.5f);
            s1 = f ? 1.f : 0.f;
            c1 += s1;
            unsigned long long ball = __ballot(f);
            if (lane == 0) wcnt1[wid] = __popcll(ball);
            if (f) {
                int pos = __popcll(ball & lt_mask);
                list1[wid * 64 + pos] = (short)j;
            }
        }
        __syncthreads();   // (1) list1/wcnt1 ready

        // ---- Layer 2: gather firing columns of W2 ----
        {
            float a0 = 0.f, a1 = 0.f, a2 = 0.f, a3 = 0.f;
            if (k2) {  // masked-off lanes skip their loads entirely
                for (int w = 0; w < 8; ++w) {
                    int cnt = wcnt1[w];
                    const short* lp = &list1[w * 64];
                    int r = 0;
                    for (; r + 4 <= cnt; r += 4) {
                        int i0 = lp[r], i1 = lp[r + 1], i2 = lp[r + 2], i3 = lp[r + 3];
                        a0 += W2T[(i0 << 9) + j];
                        a1 += W2T[(i1 << 9) + j];
                        a2 += W2T[(i2 << 9) + j];
                        a3 += W2T[(i3 << 9) + j];
                    }
                    for (; r < cnt; ++r) a0 += W2T[(lp[r] << 9) + j];
                }
            }
            float nm = mem2 * (0.2f * (1.f - s2)) + ((a0 + a1) + (a2 + a3)) + b2v;
            if (k2) mem2 = nm;
            bool f = k2 && (mem2 > 0.5f);
            s2 = f ? 1.f : 0.f;
            c2 += s2;
            unsigned long long ball = __ballot(f);
            if (lane == 0) wcnt2[wid] = __popcll(ball);
            if (f) {
                int pos = __popcll(ball & lt_mask);
                list2[wid * 64 + pos] = (short)j;
            }
        }
        __syncthreads();   // (2) list2/wcnt2 ready

        // ---- Layer 3 ----
        {
            float a0 = 0.f, a1 = 0.f, a2 = 0.f, a3 = 0.f;
            if (k3) {
                for (int w = 0; w < 8; ++w) {
                    int cnt = wcnt2[w];
                    const short* lp = &list2[w * 64];
                    int r = 0;
                    for (; r + 4 <= cnt; r += 4) {
                        int i0 = lp[r], i1 = lp[r + 1], i2 = lp[r + 2], i3 = lp[r + 3];
                        a0 += W3T[(i0 << 9) + j];
                        a1 += W3T[(i1 << 9) + j];
                        a2 += W3T[(i2 << 9) + j];
                        a3 += W3T[(i3 << 9) + j];
                    }
                    for (; r < cnt; ++r) a0 += W3T[(lp[r] << 9) + j];
                }
            }
            float nm = mem3 * (0.2f * (1.f - s3)) + ((a0 + a1) + (a2 + a3)) + b3v;
            if (k3) mem3 = nm;
            bool f = k3 && (mem3 > 0.5f);
            s3 = f ? 1.f : 0.f;
            c3 += s3;
        }
        __syncthreads();   // (3) protect list1/list2 reuse next step
    }

    // ---- epilogue ----
    const float inv_t = 1.f / (float)T_STEPS;
    out[OFF_FR1 + n * H + j] = c1 * inv_t;
    out[OFF_FR2 + n * H + j] = c2 * inv_t;
    out[OFF_FR3 + n * H + j] = c3 * inv_t;

    if (j < 16) acc10[j] = 0.f;
    if (j < 3)  rsum[j] = 0.f;
    __syncthreads();

    // outputs[n] = (ss3 @ W4.T)/T + b4   (osum is linear in s3)
    for (int o = 0; o < OUTC; ++o) {
        float v = c3 * W4[o * H + j];
        for (int m = 32; m; m >>= 1) v += __shfl_xor(v, m, 64);
        if (lane == 0) atomicAdd(&acc10[o], v);
    }
    float v1 = c1, v2 = c2, v3 = c3;
    for (int m = 32; m; m >>= 1) {
        v1 += __shfl_xor(v1, m, 64);
        v2 += __shfl_xor(v2, m, 64);
        v3 += __shfl_xor(v3, m, 64);
    }
    if (lane == 0) {
        atomicAdd(&rsum[0], v1);
        atomicAdd(&rsum[1], v2);
        atomicAdd(&rsum[2], v3);
    }
    __syncthreads();
    if (j < OUTC) out[OFF_OUT + n * OUTC + j] = acc10[j] * inv_t + b4[j];
    if (j == 0) {
        const float sc = 1.f / ((float)NBATCH * (float)H * (float)T_STEPS);
        atomicAdd(&out[OFF_LFR + 0], rsum[0] * sc);
        atomicAdd(&out[OFF_LFR + 1], rsum[1] * sc);
        atomicAdd(&out[OFF_LFR + 2], rsum[2] * sc);
    }
}

extern "C" void kernel_launch(void* const* d_in, const int* in_sizes, int n_in,
                              void* d_out, int out_size, void* d_ws, size_t ws_size,
                              hipStream_t stream)
{
    const float* x  = (const float*)d_in[0];
    const float* W1 = (const float*)d_in[1];
    const float* b1 = (const float*)d_in[2];
    const float* W2 = (const float*)d_in[3];
    const float* b2 = (const float*)d_in[4];
    const float* W3 = (const float*)d_in[5];
    const float* b3 = (const float*)d_in[6];
    const float* W4 = (const float*)d_in[7];
    const float* b4 = (const float*)d_in[8];
    const float* m1 = (const float*)d_in[9];
    const float* m2 = (const float*)d_in[10];
    const float* m3 = (const float*)d_in[11];
    float* out = (float*)d_out;

    float* W2T = (float*)d_ws;
    float* W3T = W2T + H * H;
    unsigned char* m1T = (unsigned char*)(W3T + H * H);
    unsigned char* m2T = m1T + T_STEPS * H;
    unsigned char* m3T = m2T + T_STEPS * H;

    hipLaunchKernelGGL(prep_kernel, dim3(512), dim3(256), 0, stream,
                       W2, W3, m1, m2, m3, W2T, W3T, m1T, m2T, m3T, out + OFF_LFR);
    hipLaunchKernelGGL(snn_kernel, dim3(NBATCH), dim3(512), 0, stream,
                       x, W1, b1, b2, b3, W4, b4, W2T, W3T, m1T, m2T, m3T, out);
}

// Round 2
// 4595.156 us; speedup vs baseline: 1.1270x; 1.1270x over previous
//
#include <hip/hip_runtime.h>

#define T_STEPS 784
#define H 512
#define NBATCH 128
#define OUTC 10

// out layout (floats): outputs[128*10] | fr1[128*512] | fr2 | fr3 | layer_fr[3]
#define OFF_OUT   0
#define OFF_FR1   1280
#define OFF_FR2   66816
#define OFF_FR3   132352
#define OFF_LFR   197888

__global__ __launch_bounds__(256) void prep_kernel(
    const float* __restrict__ W2, const float* __restrict__ W3,
    const float* __restrict__ m1, const float* __restrict__ m2, const float* __restrict__ m3,
    float* __restrict__ W2T, float* __restrict__ W3T,
    unsigned char* __restrict__ mP, float* __restrict__ out_tail)
{
    int tid = blockIdx.x * blockDim.x + threadIdx.x;
    int stride = gridDim.x * blockDim.x;
    // transpose W2, W3: W2T[i*H+j] = W2[j*H+i]
    for (int p = tid; p < H * H; p += stride) {
        int i = p >> 9, j = p & (H - 1);
        W2T[p] = W2[j * H + i];
        W3T[p] = W3[j * H + i];
    }
    // masks: [dim][T] fp32 -> [t][dim] packed bits (k1|k2<<1|k3<<2)
    for (int p = tid; p < T_STEPS * H; p += stride) {
        int t = p >> 9, i = p & (H - 1);
        unsigned char b = 0;
        if (m1[i * T_STEPS + t] != 0.f) b |= 1;
        if (m2[i * T_STEPS + t] != 0.f) b |= 2;
        if (m3[i * T_STEPS + t] != 0.f) b |= 4;
        mP[p] = b;
    }
    if (tid < 3) out_tail[tid] = 0.f;  // layer_fr accumulators
}

__global__ __launch_bounds__(256) void snn_kernel(
    const float* __restrict__ x,
    const float* __restrict__ W1, const float* __restrict__ b1,
    const float* __restrict__ b2, const float* __restrict__ b3,
    const float* __restrict__ W4, const float* __restrict__ b4,
    const float* __restrict__ W2T, const float* __restrict__ W3T,
    const unsigned char* __restrict__ mP,
    float* __restrict__ out)
{
    const int n = blockIdx.x;      // sample
    const int tid = threadIdx.x;   // handles neurons 2*tid, 2*tid+1
    const int lane = tid & 63;
    const int wid = tid >> 6;      // 4 waves
    const int j0 = 2 * tid;

    __shared__ float x_lds[T_STEPS];
    __shared__ short list1[H];     // per-wave segments of 128
    __shared__ short list2[H];
    __shared__ int wcnt1[4], wcnt2[4];
    __shared__ float acc10[16];
    __shared__ float rsum[3];

    for (int t = tid; t < T_STEPS; t += 256) x_lds[t] = x[n * T_STEPS + t];

    float me1 = 0.f, mo1 = 0.f, me2 = 0.f, mo2 = 0.f, me3 = 0.f, mo3 = 0.f;
    float se1 = 0.f, so1 = 0.f, se2 = 0.f, so2 = 0.f, se3 = 0.f, so3 = 0.f;
    float c1e = 0.f, c1o = 0.f, c2e = 0.f, c2o = 0.f, c3e = 0.f, c3o = 0.f;

    const float2 W1v = ((const float2*)W1)[tid];
    const float2 b1v = ((const float2*)b1)[tid];
    const float2 b2v = ((const float2*)b2)[tid];
    const float2 b3v = ((const float2*)b3)[tid];
    const unsigned long long lt_mask = (1ull << lane) - 1ull;
    const float2* __restrict__ W2T2 = (const float2*)W2T;
    const float2* __restrict__ W3T2 = (const float2*)W3T;

    // prefetch packed masks for t=0 (2 bytes: neurons j0, j0+1)
    unsigned short mb = ((const unsigned short*)mP)[tid];

    __syncthreads();

    for (int t = 0; t < T_STEPS; ++t) {
        const bool ke1 = (mb & 0x0001) != 0, ko1 = (mb & 0x0100) != 0;
        const bool ke2 = (mb & 0x0002) != 0, ko2 = (mb & 0x0200) != 0;
        const bool ke3 = (mb & 0x0004) != 0, ko3 = (mb & 0x0400) != 0;

        // ---- Layer 1 (elementwise) ----
        {
            const float xt = x_lds[t];
            float nme = me1 * (0.2f * (1.f - se1)) + xt * W1v.x + b1v.x;
            float nmo = mo1 * (0.2f * (1.f - so1)) + xt * W1v.y + b1v.y;
            if (ke1) me1 = nme;
            if (ko1) mo1 = nmo;
            bool fe = ke1 && (me1 > 0.5f);
            bool fo = ko1 && (mo1 > 0.5f);
            se1 = fe ? 1.f : 0.f;  c1e += se1;
            so1 = fo ? 1.f : 0.f;  c1o += so1;
            unsigned long long be = __ballot(fe), bo = __ballot(fo);
            int ne = __popcll(be);
            if (lane == 0) wcnt1[wid] = ne + __popcll(bo);
            if (fe) list1[wid * 128 + __popcll(be & lt_mask)] = (short)j0;
            if (fo) list1[wid * 128 + ne + __popcll(bo & lt_mask)] = (short)(j0 + 1);
        }
        // prefetch next step's masks (completes under the gathers)
        int tn = (t + 1 < T_STEPS) ? t + 1 : t;
        unsigned short mbn = ((const unsigned short*)(mP + tn * H))[tid];

        __syncthreads();   // (1) list1/wcnt1 ready

        // ---- Layer 2: gather firing columns of W2 ----
        {
            float ax0=0.f,ax1=0.f,ax2=0.f,ax3=0.f,ax4=0.f,ax5=0.f,ax6=0.f,ax7=0.f;
            float ay0=0.f,ay1=0.f,ay2=0.f,ay3=0.f,ay4=0.f,ay5=0.f,ay6=0.f,ay7=0.f;
            if (ke2 || ko2) {
                for (int w = 0; w < 4; ++w) {
                    int cnt = wcnt1[w];
                    const short* lp = &list1[w * 128];
                    int r = 0;
                    for (; r + 8 <= cnt; r += 8) {
                        short4 sa = *(const short4*)(lp + r);
                        short4 sb = *(const short4*)(lp + r + 4);
                        float2 t0 = W2T2[((int)sa.x << 8) + tid];
                        float2 t1 = W2T2[((int)sa.y << 8) + tid];
                        float2 t2 = W2T2[((int)sa.z << 8) + tid];
                        float2 t3 = W2T2[((int)sa.w << 8) + tid];
                        float2 t4 = W2T2[((int)sb.x << 8) + tid];
                        float2 t5 = W2T2[((int)sb.y << 8) + tid];
                        float2 t6 = W2T2[((int)sb.z << 8) + tid];
                        float2 t7 = W2T2[((int)sb.w << 8) + tid];
                        ax0 += t0.x; ay0 += t0.y;  ax1 += t1.x; ay1 += t1.y;
                        ax2 += t2.x; ay2 += t2.y;  ax3 += t3.x; ay3 += t3.y;
                        ax4 += t4.x; ay4 += t4.y;  ax5 += t5.x; ay5 += t5.y;
                        ax6 += t6.x; ay6 += t6.y;  ax7 += t7.x; ay7 += t7.y;
                    }
                    for (; r < cnt; ++r) {
                        float2 t0 = W2T2[((int)lp[r] << 8) + tid];
                        ax0 += t0.x; ay0 += t0.y;
                    }
                }
            }
            float sx = ((ax0+ax1)+(ax2+ax3)) + ((ax4+ax5)+(ax6+ax7));
            float sy = ((ay0+ay1)+(ay2+ay3)) + ((ay4+ay5)+(ay6+ay7));
            float nme = me2 * (0.2f * (1.f - se2)) + sx + b2v.x;
            float nmo = mo2 * (0.2f * (1.f - so2)) + sy + b2v.y;
            if (ke2) me2 = nme;
            if (ko2) mo2 = nmo;
            bool fe = ke2 && (me2 > 0.5f);
            bool fo = ko2 && (mo2 > 0.5f);
            se2 = fe ? 1.f : 0.f;  c2e += se2;
            so2 = fo ? 1.f : 0.f;  c2o += so2;
            unsigned long long be = __ballot(fe), bo = __ballot(fo);
            int ne = __popcll(be);
            if (lane == 0) wcnt2[wid] = ne + __popcll(bo);
            if (fe) list2[wid * 128 + __popcll(be & lt_mask)] = (short)j0;
            if (fo) list2[wid * 128 + ne + __popcll(bo & lt_mask)] = (short)(j0 + 1);
        }
        __syncthreads();   // (2) list2/wcnt2 ready

        // ---- Layer 3 ----
        {
            float ax0=0.f,ax1=0.f,ax2=0.f,ax3=0.f,ax4=0.f,ax5=0.f,ax6=0.f,ax7=0.f;
            float ay0=0.f,ay1=0.f,ay2=0.f,ay3=0.f,ay4=0.f,ay5=0.f,ay6=0.f,ay7=0.f;
            if (ke3 || ko3) {
                for (int w = 0; w < 4; ++w) {
                    int cnt = wcnt2[w];
                    const short* lp = &list2[w * 128];
                    int r = 0;
                    for (; r + 8 <= cnt; r += 8) {
                        short4 sa = *(const short4*)(lp + r);
                        short4 sb = *(const short4*)(lp + r + 4);
                        float2 t0 = W3T2[((int)sa.x << 8) + tid];
                        float2 t1 = W3T2[((int)sa.y << 8) + tid];
                        float2 t2 = W3T2[((int)sa.z << 8) + tid];
                        float2 t3 = W3T2[((int)sa.w << 8) + tid];
                        float2 t4 = W3T2[((int)sb.x << 8) + tid];
                        float2 t5 = W3T2[((int)sb.y << 8) + tid];
                        float2 t6 = W3T2[((int)sb.z << 8) + tid];
                        float2 t7 = W3T2[((int)sb.w << 8) + tid];
                        ax0 += t0.x; ay0 += t0.y;  ax1 += t1.x; ay1 += t1.y;
                        ax2 += t2.x; ay2 += t2.y;  ax3 += t3.x; ay3 += t3.y;
                        ax4 += t4.x; ay4 += t4.y;  ax5 += t5.x; ay5 += t5.y;
                        ax6 += t6.x; ay6 += t6.y;  ax7 += t7.x; ay7 += t7.y;
                    }
                    for (; r < cnt; ++r) {
                        float2 t0 = W3T2[((int)lp[r] << 8) + tid];
                        ax0 += t0.x; ay0 += t0.y;
                    }
                }
            }
            float sx = ((ax0+ax1)+(ax2+ax3)) + ((ax4+ax5)+(ax6+ax7));
            float sy = ((ay0+ay1)+(ay2+ay3)) + ((ay4+ay5)+(ay6+ay7));
            float nme = me3 * (0.2f * (1.f - se3)) + sx + b3v.x;
            float nmo = mo3 * (0.2f * (1.f - so3)) + sy + b3v.y;
            if (ke3) me3 = nme;
            if (ko3) mo3 = nmo;
            bool fe = ke3 && (me3 > 0.5f);
            bool fo = ko3 && (mo3 > 0.5f);
            se3 = fe ? 1.f : 0.f;  c3e += se3;
            so3 = fo ? 1.f : 0.f;  c3o += so3;
        }
        mb = mbn;
        // no barrier 3 needed: next step's list1 writes can't race list2 readers
    }

    // ---- epilogue ----
    const float inv_t = 1.f / (float)T_STEPS;
    ((float2*)(out + OFF_FR1 + n * H))[tid] = make_float2(c1e * inv_t, c1o * inv_t);
    ((float2*)(out + OFF_FR2 + n * H))[tid] = make_float2(c2e * inv_t, c2o * inv_t);
    ((float2*)(out + OFF_FR3 + n * H))[tid] = make_float2(c3e * inv_t, c3o * inv_t);

    if (tid < 16) acc10[tid] = 0.f;
    if (tid < 3)  rsum[tid] = 0.f;
    __syncthreads();

    // outputs[n] = (ss3 @ W4.T)/T + b4   (osum is linear in s3)
    for (int o = 0; o < OUTC; ++o) {
        float2 w4v = ((const float2*)(W4 + o * H))[tid];
        float v = c3e * w4v.x + c3o * w4v.y;
        for (int m = 32; m; m >>= 1) v += __shfl_xor(v, m, 64);
        if (lane == 0) atomicAdd(&acc10[o], v);
    }
    float v1 = c1e + c1o, v2 = c2e + c2o, v3 = c3e + c3o;
    for (int m = 32; m; m >>= 1) {
        v1 += __shfl_xor(v1, m, 64);
        v2 += __shfl_xor(v2, m, 64);
        v3 += __shfl_xor(v3, m, 64);
    }
    if (lane == 0) {
        atomicAdd(&rsum[0], v1);
        atomicAdd(&rsum[1], v2);
        atomicAdd(&rsum[2], v3);
    }
    __syncthreads();
    if (tid < OUTC) out[OFF_OUT + n * OUTC + tid] = acc10[tid] * inv_t + b4[tid];
    if (tid == 0) {
        const float sc = 1.f / ((float)NBATCH * (float)H * (float)T_STEPS);
        atomicAdd(&out[OFF_LFR + 0], rsum[0] * sc);
        atomicAdd(&out[OFF_LFR + 1], rsum[1] * sc);
        atomicAdd(&out[OFF_LFR + 2], rsum[2] * sc);
    }
}

extern "C" void kernel_launch(void* const* d_in, const int* in_sizes, int n_in,
                              void* d_out, int out_size, void* d_ws, size_t ws_size,
                              hipStream_t stream)
{
    const float* x  = (const float*)d_in[0];
    const float* W1 = (const float*)d_in[1];
    const float* b1 = (const float*)d_in[2];
    const float* W2 = (const float*)d_in[3];
    const float* b2 = (const float*)d_in[4];
    const float* W3 = (const float*)d_in[5];
    const float* b3 = (const float*)d_in[6];
    const float* W4 = (const float*)d_in[7];
    const float* b4 = (const float*)d_in[8];
    const float* m1 = (const float*)d_in[9];
    const float* m2 = (const float*)d_in[10];
    const float* m3 = (const float*)d_in[11];
    float* out = (float*)d_out;

    float* W2T = (float*)d_ws;
    float* W3T = W2T + H * H;
    unsigned char* mP = (unsigned char*)(W3T + H * H);

    hipLaunchKernelGGL(prep_kernel, dim3(512), dim3(256), 0, stream,
                       W2, W3, m1, m2, m3, W2T, W3T, mP, out + OFF_LFR);
    hipLaunchKernelGGL(snn_kernel, dim3(NBATCH), dim3(256), 0, stream,
                       x, W1, b1, b2, b3, W4, b4, W2T, W3T, mP, out);
}

// Round 3
// 2872.781 us; speedup vs baseline: 1.8026x; 1.5995x over previous
//
#include <hip/hip_runtime.h>

#define T_STEPS 784
#define H 512
#define NBATCH 128
#define OUTC 10
#define ZROW 512   // zero-row index appended to W2T/W3T

// out layout (floats): outputs[128*10] | fr1[128*512] | fr2 | fr3 | layer_fr[3]
#define OFF_OUT   0
#define OFF_FR1   1280
#define OFF_FR2   66816
#define OFF_FR3   132352
#define OFF_LFR   197888

__global__ __launch_bounds__(256) void prep_kernel(
    const float* __restrict__ W2, const float* __restrict__ W3,
    const float* __restrict__ m1, const float* __restrict__ m2, const float* __restrict__ m3,
    float* __restrict__ W2T, float* __restrict__ W3T,
    unsigned char* __restrict__ mP, float* __restrict__ out_tail)
{
    int tid = blockIdx.x * blockDim.x + threadIdx.x;
    int stride = gridDim.x * blockDim.x;
    // transpose W2, W3: W2T[i*H+j] = W2[j*H+i]
    for (int p = tid; p < H * H; p += stride) {
        int i = p >> 9, j = p & (H - 1);
        W2T[p] = W2[j * H + i];
        W3T[p] = W3[j * H + i];
    }
    // zero row (index 512) for list padding
    for (int p = tid; p < H; p += stride) {
        W2T[H * H + p] = 0.f;
        W3T[H * H + p] = 0.f;
    }
    // masks: [dim][T] fp32 -> [t][dim] packed bits (k1|k2<<1|k3<<2)
    for (int p = tid; p < T_STEPS * H; p += stride) {
        int t = p >> 9, i = p & (H - 1);
        unsigned char b = 0;
        if (m1[i * T_STEPS + t] != 0.f) b |= 1;
        if (m2[i * T_STEPS + t] != 0.f) b |= 2;
        if (m3[i * T_STEPS + t] != 0.f) b |= 4;
        mP[p] = b;
    }
    if (tid < 3) out_tail[tid] = 0.f;  // layer_fr accumulators
}

__global__ __launch_bounds__(512, 2) void snn_kernel(
    const float* __restrict__ x,
    const float* __restrict__ W1, const float* __restrict__ b1,
    const float* __restrict__ b2, const float* __restrict__ b3,
    const float* __restrict__ W4, const float* __restrict__ b4,
    const float* __restrict__ W2T, const float* __restrict__ W3T,
    const unsigned char* __restrict__ mP,
    float* __restrict__ out)
{
    const int n = blockIdx.x;      // sample
    const int j = threadIdx.x;     // neuron
    const int lane = j & 63;
    const int wid = j >> 6;        // 8 waves

    __shared__ float x_lds[T_STEPS];
    __shared__ short list1[H + 32];   // merged firing list, padded with ZROW
    __shared__ short list2[H + 32];
    __shared__ int wcnt1[8], wcnt2[8];
    __shared__ float acc10[16];
    __shared__ float rsum[3];

    for (int t = j; t < T_STEPS; t += 512) x_lds[t] = x[n * T_STEPS + t];

    float mem1 = 0.f, mem2 = 0.f, mem3 = 0.f;
    float s1 = 0.f, s2 = 0.f, s3 = 0.f;
    float c1 = 0.f, c2 = 0.f, c3 = 0.f;
    const float w1  = W1[j];
    const float b1v = b1[j], b2v = b2[j], b3v = b3[j];
    const unsigned long long lt_mask = (1ull << lane) - 1ull;
    const float* __restrict__ Wp2 = W2T + j;
    const float* __restrict__ Wp3 = W3T + j;

    unsigned char mb = mP[j];   // masks for t=0
    __syncthreads();

    for (int t = 0; t < T_STEPS; ++t) {
        const bool k1 = (mb & 1) != 0;
        const bool k2 = (mb & 2) != 0;
        const bool k3 = (mb & 4) != 0;

        // ---- Layer 1 (elementwise) ----
        float nm1 = mem1 * (0.2f * (1.f - s1)) + x_lds[t] * w1 + b1v;
        if (k1) mem1 = nm1;
        bool f1 = k1 && (mem1 > 0.5f);
        s1 = f1 ? 1.f : 0.f;  c1 += s1;
        {
            unsigned long long ball = __ballot(f1);
            if (lane == 0) wcnt1[wid] = __popcll(ball);
            int pos = __popcll(ball & lt_mask);
            // prefetch next step's masks (flies under the gathers)
            int tn = (t + 1 < T_STEPS) ? t + 1 : t;
            unsigned char mbn = mP[tn * H + j];

            __syncthreads();   // A1: counts visible
            int base = 0, cnt = 0;
            #pragma unroll
            for (int w = 0; w < 8; ++w) {
                int c = wcnt1[w];
                if (w < wid) base += c;
                cnt += c;
            }
            if (f1) list1[base + pos] = (short)j;
            int cntp = (cnt + 31) & ~31;
            if (j < cntp - cnt) list1[cnt + j] = ZROW;
            __syncthreads();   // B1: list1 ready (padded)

            // ---- Layer 2: gather firing columns of W2 ----
            float a0=0.f,a1=0.f,a2=0.f,a3=0.f,a4=0.f,a5=0.f,a6=0.f,a7=0.f;
            if (k2) {
                for (int r = 0; r < cntp; r += 32) {
                    const short4* lp = (const short4*)(list1 + r);
                    float g[32];
                    #pragma unroll
                    for (int q = 0; q < 8; ++q) {
                        short4 s4 = lp[q];
                        g[4*q+0] = Wp2[(int)s4.x << 9];
                        g[4*q+1] = Wp2[(int)s4.y << 9];
                        g[4*q+2] = Wp2[(int)s4.z << 9];
                        g[4*q+3] = Wp2[(int)s4.w << 9];
                    }
                    a0 += g[0];  a1 += g[1];  a2 += g[2];  a3 += g[3];
                    a4 += g[4];  a5 += g[5];  a6 += g[6];  a7 += g[7];
                    a0 += g[8];  a1 += g[9];  a2 += g[10]; a3 += g[11];
                    a4 += g[12]; a5 += g[13]; a6 += g[14]; a7 += g[15];
                    a0 += g[16]; a1 += g[17]; a2 += g[18]; a3 += g[19];
                    a4 += g[20]; a5 += g[21]; a6 += g[22]; a7 += g[23];
                    a0 += g[24]; a1 += g[25]; a2 += g[26]; a3 += g[27];
                    a4 += g[28]; a5 += g[29]; a6 += g[30]; a7 += g[31];
                }
            }
            float sx = ((a0+a1)+(a2+a3)) + ((a4+a5)+(a6+a7));
            float nm2 = mem2 * (0.2f * (1.f - s2)) + sx + b2v;
            if (k2) mem2 = nm2;
            mb = mbn;  // commit mask prefetch
        }
        bool f2 = k2 && (mem2 > 0.5f);
        s2 = f2 ? 1.f : 0.f;  c2 += s2;
        {
            unsigned long long ball = __ballot(f2);
            if (lane == 0) wcnt2[wid] = __popcll(ball);
            int pos = __popcll(ball & lt_mask);

            __syncthreads();   // A2: counts visible
            int base = 0, cnt = 0;
            #pragma unroll
            for (int w = 0; w < 8; ++w) {
                int c = wcnt2[w];
                if (w < wid) base += c;
                cnt += c;
            }
            if (f2) list2[base + pos] = (short)j;
            int cntp = (cnt + 31) & ~31;
            if (j < cntp - cnt) list2[cnt + j] = ZROW;
            __syncthreads();   // B2: list2 ready (padded)

            // ---- Layer 3: gather firing columns of W3 ----
            float a0=0.f,a1=0.f,a2=0.f,a3=0.f,a4=0.f,a5=0.f,a6=0.f,a7=0.f;
            if (k3) {
                for (int r = 0; r < cntp; r += 32) {
                    const short4* lp = (const short4*)(list2 + r);
                    float g[32];
                    #pragma unroll
                    for (int q = 0; q < 8; ++q) {
                        short4 s4 = lp[q];
                        g[4*q+0] = Wp3[(int)s4.x << 9];
                        g[4*q+1] = Wp3[(int)s4.y << 9];
                        g[4*q+2] = Wp3[(int)s4.z << 9];
                        g[4*q+3] = Wp3[(int)s4.w << 9];
                    }
                    a0 += g[0];  a1 += g[1];  a2 += g[2];  a3 += g[3];
                    a4 += g[4];  a5 += g[5];  a6 += g[6];  a7 += g[7];
                    a0 += g[8];  a1 += g[9];  a2 += g[10]; a3 += g[11];
                    a4 += g[12]; a5 += g[13]; a6 += g[14]; a7 += g[15];
                    a0 += g[16]; a1 += g[17]; a2 += g[18]; a3 += g[19];
                    a4 += g[20]; a5 += g[21]; a6 += g[22]; a7 += g[23];
                    a0 += g[24]; a1 += g[25]; a2 += g[26]; a3 += g[27];
                    a4 += g[28]; a5 += g[29]; a6 += g[30]; a7 += g[31];
                }
            }
            float sx = ((a0+a1)+(a2+a3)) + ((a4+a5)+(a6+a7));
            float nm3 = mem3 * (0.2f * (1.f - s3)) + sx + b3v;
            if (k3) mem3 = nm3;
        }
        bool f3 = k3 && (mem3 > 0.5f);
        s3 = f3 ? 1.f : 0.f;  c3 += s3;
        // no 3rd barrier: next step's list1 writes are fenced by A1/B1
    }

    // ---- epilogue ----
    const float inv_t = 1.f / (float)T_STEPS;
    out[OFF_FR1 + n * H + j] = c1 * inv_t;
    out[OFF_FR2 + n * H + j] = c2 * inv_t;
    out[OFF_FR3 + n * H + j] = c3 * inv_t;

    if (j < 16) acc10[j] = 0.f;
    if (j < 3)  rsum[j] = 0.f;
    __syncthreads();

    // outputs[n] = (ss3 @ W4.T)/T + b4  (osum linear in s3)
    for (int o = 0; o < OUTC; ++o) {
        float v = c3 * W4[o * H + j];
        for (int m = 32; m; m >>= 1) v += __shfl_xor(v, m, 64);
        if (lane == 0) atomicAdd(&acc10[o], v);
    }
    float v1 = c1, v2 = c2, v3 = c3;
    for (int m = 32; m; m >>= 1) {
        v1 += __shfl_xor(v1, m, 64);
        v2 += __shfl_xor(v2, m, 64);
        v3 += __shfl_xor(v3, m, 64);
    }
    if (lane == 0) {
        atomicAdd(&rsum[0], v1);
        atomicAdd(&rsum[1], v2);
        atomicAdd(&rsum[2], v3);
    }
    __syncthreads();
    if (j < OUTC) out[OFF_OUT + n * OUTC + j] = acc10[j] * inv_t + b4[j];
    if (j == 0) {
        const float sc = 1.f / ((float)NBATCH * (float)H * (float)T_STEPS);
        atomicAdd(&out[OFF_LFR + 0], rsum[0] * sc);
        atomicAdd(&out[OFF_LFR + 1], rsum[1] * sc);
        atomicAdd(&out[OFF_LFR + 2], rsum[2] * sc);
    }
}

extern "C" void kernel_launch(void* const* d_in, const int* in_sizes, int n_in,
                              void* d_out, int out_size, void* d_ws, size_t ws_size,
                              hipStream_t stream)
{
    const float* x  = (const float*)d_in[0];
    const float* W1 = (const float*)d_in[1];
    const float* b1 = (const float*)d_in[2];
    const float* W2 = (const float*)d_in[3];
    const float* b2 = (const float*)d_in[4];
    const float* W3 = (const float*)d_in[5];
    const float* b3 = (const float*)d_in[6];
    const float* W4 = (const float*)d_in[7];
    const float* b4 = (const float*)d_in[8];
    const float* m1 = (const float*)d_in[9];
    const float* m2 = (const float*)d_in[10];
    const float* m3 = (const float*)d_in[11];
    float* out = (float*)d_out;

    float* W2T = (float*)d_ws;                       // (H+1) x H
    float* W3T = W2T + (H + 1) * H;                  // (H+1) x H
    unsigned char* mP = (unsigned char*)(W3T + (H + 1) * H);

    hipLaunchKernelGGL(prep_kernel, dim3(512), dim3(256), 0, stream,
                       W2, W3, m1, m2, m3, W2T, W3T, mP, out + OFF_LFR);
    hipLaunchKernelGGL(snn_kernel, dim3(NBATCH), dim3(512), 0, stream,
                       x, W1, b1, b2, b3, W4, b4, W2T, W3T, mP, out);
}